// Round 11
// baseline (523.001 us; speedup 1.0000x reference)
//
#include <hip/hip_runtime.h>

// ---------- types ----------
typedef __attribute__((ext_vector_type(8))) short short8;
typedef __attribute__((ext_vector_type(4))) float f32x4;

__device__ __forceinline__ unsigned short f2bf(float f) {
    union { float f; unsigned u; } v; v.f = f;
    unsigned r = v.u + 0x7FFFu + ((v.u >> 16) & 1u);   // RNE
    return (unsigned short)(r >> 16);
}

// ---------- K1: tiled transpose fp32 [G][K][N] -> bf16 [G][Np][K] ----------
__global__ __launch_bounds__(256)
void transpose_kernel(const float* __restrict__ X, unsigned short* __restrict__ Y,
                      int K, int N, int Np) {
    __shared__ float tile[32][33];
    int g = blockIdx.z;
    const float* Xg = X + (long)g * K * N;
    unsigned short* Yg = Y + (long)g * Np * K;
    int k0 = blockIdx.x * 32, n0 = blockIdx.y * 32;
    int tx = threadIdx.x & 31, ty = threadIdx.x >> 5;
#pragma unroll
    for (int i = 0; i < 4; ++i) {
        int kk = ty + i * 8;
        int n = n0 + tx;
        tile[kk][tx] = (n < N) ? Xg[(long)(k0 + kk) * N + n] : 0.0f;
    }
    __syncthreads();
#pragma unroll
    for (int i = 0; i < 4; ++i) {
        int nn = ty + i * 8;
        Yg[(long)(n0 + nn) * K + k0 + tx] = f2bf(tile[tx][nn]);
    }
}

// ---------- K2: fuzzy membership -> bf16 [R*B, F]; r==0 slice also emits data_bf ----------
__global__ __launch_bounds__(256)
void fuzzy_kernel(const float* __restrict__ data, const float* __restrict__ proto,
                  const float* __restrict__ var, unsigned short* __restrict__ fuzzy,
                  unsigned short* __restrict__ data_bf) {
    int t = threadIdx.x;
    int rb = blockIdx.x * 2 + (t >> 7);          // 32768 blocks x 2 rows
    int r = rb >> 11, b = rb & 2047;
    int f = (t & 127) * 4;
    float4 d = *(const float4*)(data + (long)b * 512 + f);
    float4 p = *(const float4*)(proto + (long)r * 512 + f);
    float4 w = *(const float4*)(var + (long)r * 512 + f);
    ushort4 o;
    float x;
    x = d.x - p.x; o.x = f2bf(__expf(-(x * x) / (2.f * w.x * w.x)));
    x = d.y - p.y; o.y = f2bf(__expf(-(x * x) / (2.f * w.y * w.y)));
    x = d.z - p.z; o.z = f2bf(__expf(-(x * x) / (2.f * w.z * w.z)));
    x = d.w - p.w; o.w = f2bf(__expf(-(x * x) / (2.f * w.w * w.w)));
    *(ushort4*)(fuzzy + (long)rb * 512 + f) = o;
    if (r == 0) {   // fold data -> bf16 conversion into the r==0 slice
        ushort4 od;
        od.x = f2bf(d.x); od.y = f2bf(d.y); od.z = f2bf(d.z); od.w = f2bf(d.w);
        *(ushort4*)(data_bf + (long)b * 512 + f) = od;
    }
}

#define RING_WAIT_BARRIER(n)                                        \
    asm volatile("s_waitcnt vmcnt(" #n ")" ::: "memory");           \
    __builtin_amdgcn_sched_barrier(0);                              \
    __builtin_amdgcn_s_barrier();                                   \
    __builtin_amdgcn_sched_barrier(0);

// ---------- K3: 256x256 ring-4 bf16 MFMA GEMM + full-128KB-restage C epilogue ----------
// (K-loop/epilogue structure identical to rounds 4/5/8/10 — only ADDRESSING is parameterized)
// aT: A layout 0=row-major [M][K], 1=tile-major [M/256][K/256][256][256]
// cT: C layout (EPI0) 0=row-major [M][N], 1=tile-major [M/256][N/256][256][256]
// EPI: 0 = bf16 C store via full LDS re-stage, 1 = fused dot w3 -> atomicAdd fslog.
template<int EPI, bool RELU>
__global__ __launch_bounds__(512, 2)
void gemm256_kernel(const unsigned short* __restrict__ A,
                    const unsigned short* __restrict__ Bt,
                    const float* __restrict__ bias,
                    void* __restrict__ Cptr,
                    const float* __restrict__ w3,
                    float* __restrict__ fslog,
                    int nM, int nN, int K,
                    long sAg, long sBg, long sCg, int sBiasG,
                    int aT, int cT) {
    unsigned tot = gridDim.x, bid = blockIdx.x;
    unsigned sw = (bid & 7u) * (tot >> 3) + (bid >> 3);
    unsigned pg = (unsigned)(nM * nN);
    unsigned g = sw / pg;
    unsigned rem = sw - g * pg;
    const int m0 = (int)(rem / (unsigned)nN) * 256;
    const int n0 = (int)(rem % (unsigned)nN) * 256;
    const int N = nN * 256;
    A += (long)g * sAg; Bt += (long)g * sBg; bias += (long)g * sBiasG;

    __shared__ __align__(16) unsigned short lds[8][8192];   // [0..3]=A ring, [4..7]=B ring

    const int tid = threadIdx.x;
    const int lane = tid & 63;
    const int w = tid >> 6;
    const int wm = w >> 2, wn = w & 3;
    const int r16 = lane & 15, kg = lane >> 4;

    f32x4 acc[8][4];
#pragma unroll
    for (int i = 0; i < 8; ++i)
#pragma unroll
        for (int j = 0; j < 4; ++j) {
            f32x4 z = {0.f, 0.f, 0.f, 0.f};
            acc[i][j] = z;
        }

    const int nsteps = K >> 5;
    const long aRowStride = aT ? 256 : K;

    auto STAGE = [&](int slot, int kt) {
        const int k0 = kt << 5;
        const long aBase = aT
            ? (((long)((m0 >> 8) * (K >> 8) + (k0 >> 8))) << 16) + (k0 & 255)
            : (long)m0 * K + k0;
#pragma unroll
        for (int j = 0; j < 2; ++j) {
            int f = j * 512 + tid;
            int row = f >> 2, sl = f & 3;
            int kk = (sl ^ ((row >> 1) & 3)) << 3;     // T2 inverse swizzle on source
            const unsigned short* ga = A + aBase + (long)row * aRowStride + kk;
            __builtin_amdgcn_global_load_lds(
                (const __attribute__((address_space(1))) void*)ga,
                (__attribute__((address_space(3))) void*)(&lds[slot][0] + (j * 512 + w * 64) * 8),
                16, 0, 0);
            const unsigned short* gb = Bt + (long)(n0 + row) * K + k0 + kk;
            __builtin_amdgcn_global_load_lds(
                (const __attribute__((address_space(1))) void*)gb,
                (__attribute__((address_space(3))) void*)(&lds[4 + slot][0] + (j * 512 + w * 64) * 8),
                16, 0, 0);
        }
    };

    auto COMPUTE = [&](int slot) {
        short8 aF[8], bF[4];
#pragma unroll
        for (int mt = 0; mt < 8; ++mt) {
            int R = wm * 128 + mt * 16 + r16;
            aF[mt] = *(const short8*)(&lds[slot][0] + R * 32 + ((kg ^ ((R >> 1) & 3)) << 3));
        }
#pragma unroll
        for (int nt = 0; nt < 4; ++nt) {
            int R = wn * 64 + nt * 16 + r16;
            bF[nt] = *(const short8*)(&lds[4 + slot][0] + R * 32 + ((kg ^ ((R >> 1) & 3)) << 3));
        }
        __builtin_amdgcn_s_setprio(1);
#pragma unroll
        for (int mt = 0; mt < 8; ++mt)
#pragma unroll
            for (int nt = 0; nt < 4; ++nt)
                acc[mt][nt] = __builtin_amdgcn_mfma_f32_16x16x32_bf16(
                    aF[mt], bF[nt], acc[mt][nt], 0, 0, 0);
        __builtin_amdgcn_s_setprio(0);
        asm volatile("" ::: "memory");
        __builtin_amdgcn_s_barrier();          // all waves' ds_reads of this slot done
        __builtin_amdgcn_sched_barrier(0);
    };

    STAGE(0, 0); STAGE(1, 1); STAGE(2, 2);
    for (int t = 0; t <= nsteps - 3; ++t) {
        if (t + 3 < nsteps) STAGE((t + 3) & 3, t + 3);
        RING_WAIT_BARRIER(8);
        COMPUTE(t & 3);
    }
    { RING_WAIT_BARRIER(4); COMPUTE((nsteps - 2) & 3); }
    { RING_WAIT_BARRIER(0); COMPUTE((nsteps - 1) & 3); }

    // ---------- epilogue ----------
    if constexpr (EPI == 1) {
        float w3v[4], bv[4];
#pragma unroll
        for (int nt = 0; nt < 4; ++nt) {
            int col = n0 + wn * 64 + nt * 16 + r16;
            w3v[nt] = w3[col];
            bv[nt] = bias[col];
        }
#pragma unroll
        for (int mt = 0; mt < 8; ++mt) {
#pragma unroll
            for (int j = 0; j < 4; ++j) {
                float p = 0.f;
#pragma unroll
                for (int nt = 0; nt < 4; ++nt) {
                    float v = acc[mt][nt][j] + bv[nt];
                    if (RELU) v = fmaxf(v, 0.f);
                    p += v * w3v[nt];
                }
                p += __shfl_xor(p, 1, 64);
                p += __shfl_xor(p, 2, 64);
                p += __shfl_xor(p, 4, 64);
                p += __shfl_xor(p, 8, 64);
                if (r16 == 0) {
                    int row = m0 + wm * 128 + mt * 16 + kg * 4 + j;
                    atomicAdd(&fslog[row], p);
                }
            }
        }
    } else {
        // full 256x256 C tile (bias+relu+bf16) into 128KB LDS, then coalesced stores
        unsigned short* ldsC = &lds[0][0];
        float bv[4];
#pragma unroll
        for (int nt = 0; nt < 4; ++nt) bv[nt] = bias[n0 + wn * 64 + nt * 16 + r16];
#pragma unroll
        for (int mt = 0; mt < 8; ++mt) {
            int rr = wm * 128 + mt * 16 + kg * 4;
#pragma unroll
            for (int nt = 0; nt < 4; ++nt) {
                int cc = wn * 64 + nt * 16 + r16;
#pragma unroll
                for (int j = 0; j < 4; ++j) {
                    float v = acc[mt][nt][j] + bv[nt];
                    if (RELU) v = fmaxf(v, 0.f);
                    ldsC[(rr + j) * 256 + cc] = f2bf(v);
                }
            }
        }
        __syncthreads();
        unsigned short* Cg = (unsigned short*)Cptr + (long)g * sCg;
        if (cT) {
            // tile-major: one perfectly-sequential 128KB burst per block
            unsigned short* Ct = Cg + (((long)((m0 >> 8) * (N >> 8) + (n0 >> 8))) << 16);
#pragma unroll
            for (int rnd = 0; rnd < 16; ++rnd) {
                int idx = rnd * 512 + tid;          // row*256 + c8*8 == idx*8
                short8 vv = *(const short8*)(ldsC + idx * 8);
                *(short8*)(Ct + (long)idx * 8) = vv;
            }
        } else {
#pragma unroll
            for (int rnd = 0; rnd < 16; ++rnd) {
                int idx = rnd * 512 + tid;
                int row = idx >> 5;
                int c8 = idx & 31;
                short8 vv = *(const short8*)(ldsC + row * 256 + c8 * 8);
                *(short8*)(Cg + (long)(m0 + row) * N + n0 + c8 * 8) = vv;
            }
        }
    }
}

// ---------- K3b: 128x128 GEMM (m97 structure); EPI 3 = fused fire-weighted atomic mix ----------
// aT: A layout 0=row-major, 1=tile-major [M/256][K/256][256][256] (m0 multiple of 128)
template<int EPI, bool RELU>
__global__ __launch_bounds__(256, 2)
void gemm_kernel(const unsigned short* __restrict__ A,
                 const unsigned short* __restrict__ Bt,
                 const float* __restrict__ bias,
                 void* __restrict__ Cptr,
                 int nM, int nN, int K,
                 long sAg, long sBg, long sCg, int sBiasG, int biasN,
                 const float* __restrict__ fire, float* __restrict__ mix, int r0,
                 int aT) {
    unsigned tot = gridDim.x;
    unsigned bid = blockIdx.x;
    unsigned sw = (tot & 7u) == 0 ? (bid & 7u) * (tot >> 3) + (bid >> 3) : bid;
    unsigned pg = (unsigned)nM * (unsigned)nN;
    unsigned g = sw / pg;
    unsigned rem = sw - g * pg;
    unsigned mt_ = rem / (unsigned)nN;
    unsigned nt_ = rem - mt_ * (unsigned)nN;
    const int N = nN * 128;
    A += (long)g * sAg;
    Bt += (long)g * sBg;
    bias += (long)g * sBiasG;
    const int m0 = (int)mt_ * 128;
    const int n0 = (int)nt_ * 128;

    __shared__ __align__(16) unsigned short ldsA[128 * 32];
    __shared__ __align__(16) unsigned short ldsB[128 * 32];

    const int tid = threadIdx.x;
    const int lane = tid & 63;
    const int w = tid >> 6;
    const int wm = w >> 1, wn = w & 1;
    const int r16 = lane & 15, kg = lane >> 4;

    f32x4 acc[4][4];
#pragma unroll
    for (int i = 0; i < 4; ++i)
#pragma unroll
        for (int j = 0; j < 4; ++j) {
            f32x4 z = {0.f, 0.f, 0.f, 0.f};
            acc[i][j] = z;
        }

    const long aRowStride = aT ? 256 : K;

    for (int k0 = 0; k0 < K; k0 += 32) {
        const long aBase = aT
            ? (((long)((m0 >> 8) * (K >> 8) + (k0 >> 8))) << 16) + (long)(m0 & 255) * 256 + (k0 & 255)
            : (long)m0 * K + k0;
#pragma unroll
        for (int j = 0; j < 2; ++j) {
            int t = j * 256 + tid;
            int row = t >> 2, kc = (t & 3) * 8;
            const unsigned short* ga = A + aBase + (long)row * aRowStride + kc;
            __builtin_amdgcn_global_load_lds(
                (const __attribute__((address_space(1))) void*)ga,
                (__attribute__((address_space(3))) void*)(ldsA + (j * 256 + w * 64) * 8),
                16, 0, 0);
            const unsigned short* gb = Bt + (long)(n0 + row) * K + k0 + kc;
            __builtin_amdgcn_global_load_lds(
                (const __attribute__((address_space(1))) void*)gb,
                (__attribute__((address_space(3))) void*)(ldsB + (j * 256 + w * 64) * 8),
                16, 0, 0);
        }
        __syncthreads();
        short8 aF[4], bF[4];
#pragma unroll
        for (int mt = 0; mt < 4; ++mt)
            aF[mt] = *(const short8*)(ldsA + (wm * 64 + mt * 16 + r16) * 32 + kg * 8);
#pragma unroll
        for (int nt = 0; nt < 4; ++nt)
            bF[nt] = *(const short8*)(ldsB + (wn * 64 + nt * 16 + r16) * 32 + kg * 8);
#pragma unroll
        for (int mt = 0; mt < 4; ++mt)
#pragma unroll
            for (int nt = 0; nt < 4; ++nt)
                acc[mt][nt] = __builtin_amdgcn_mfma_f32_16x16x32_bf16(
                    aF[mt], bF[nt], acc[mt][nt], 0, 0, 0);
        __syncthreads();
    }

    if constexpr (EPI == 3) {
        float bv[4];
#pragma unroll
        for (int nt = 0; nt < 4; ++nt) {
            int col = n0 + wn * 64 + nt * 16 + r16;
            bv[nt] = (col < biasN) ? bias[col] : 0.f;
        }
#pragma unroll
        for (int mt = 0; mt < 4; ++mt) {
#pragma unroll
            for (int j = 0; j < 4; ++j) {
                int row = m0 + wm * 64 + mt * 16 + kg * 4 + j;   // batch index b
                float f = fire[row * 32 + r0 + (int)g];
#pragma unroll
                for (int nt = 0; nt < 4; ++nt) {
                    int col = n0 + wn * 64 + nt * 16 + r16;
                    float v = acc[mt][nt][j] + bv[nt];
                    atomicAdd(&mix[row * 128 + col], f * v);
                }
            }
        }
    } else {
#pragma unroll
        for (int nt = 0; nt < 4; ++nt) {
            int col = n0 + wn * 64 + nt * 16 + r16;
            float bv = (col < biasN) ? bias[col] : 0.f;
#pragma unroll
            for (int mt = 0; mt < 4; ++mt) {
#pragma unroll
                for (int j = 0; j < 4; ++j) {
                    int row = m0 + wm * 64 + mt * 16 + kg * 4 + j;
                    float v = acc[mt][nt][j] + bv;
                    if (RELU) v = fmaxf(v, 0.f);
                    ((float*)Cptr)[(long)g * sCg + (long)row * N + col] = v;
                }
            }
        }
    }
}

// ---------- K5: fire = softmax over rules ----------
__global__ __launch_bounds__(256)
void fire_kernel(const float* __restrict__ fslog, float* __restrict__ fire) {
    int b = blockIdx.x * 256 + threadIdx.x;
    float v[32];
    float mx = -1e30f;
#pragma unroll
    for (int r = 0; r < 32; ++r) { v[r] = fslog[r * 2048 + b]; mx = fmaxf(mx, v[r]); }
    float s = 0.f;
#pragma unroll
    for (int r = 0; r < 32; ++r) { v[r] = __expf(v[r] - mx); s += v[r]; }
    float inv = 1.f / s;
#pragma unroll
    for (int r = 0; r < 32; ++r) fire[b * 32 + r] = v[r] * inv;
}

// ---------- K7: class softmax ----------
__global__ __launch_bounds__(128)
void softmax_out_kernel(const float* __restrict__ mix, float* __restrict__ out) {
    int b = blockIdx.x, c = threadIdx.x;
    __shared__ float redm[2], reds[2];
    float val = (c < 100) ? mix[b * 128 + c] : -1e30f;
    float m = val;
#pragma unroll
    for (int off = 32; off; off >>= 1) m = fmaxf(m, __shfl_xor(m, off, 64));
    int lane = c & 63, wv = c >> 6;
    if (lane == 0) redm[wv] = m;
    __syncthreads();
    m = fmaxf(redm[0], redm[1]);
    float e = (c < 100) ? __expf(val - m) : 0.f;
    float s = e;
#pragma unroll
    for (int off = 32; off; off >>= 1) s += __shfl_xor(s, off, 64);
    if (lane == 0) reds[wv] = s;
    __syncthreads();
    s = reds[0] + reds[1];
    if (c < 100) out[b * 100 + c] = e / s;
}

// ---------- launch ----------
extern "C" void kernel_launch(void* const* d_in, const int* in_sizes, int n_in,
                              void* d_out, int out_size, void* d_ws, size_t ws_size,
                              hipStream_t stream) {
    const float* data  = (const float*)d_in[0];
    const float* proto = (const float*)d_in[1];
    const float* var   = (const float*)d_in[2];
    const float* fs_w1 = (const float*)d_in[3];
    const float* fs_b1 = (const float*)d_in[4];
    const float* fs_w2 = (const float*)d_in[5];
    const float* fs_b2 = (const float*)d_in[6];
    const float* fs_w3 = (const float*)d_in[7];
    const float* cq_w1 = (const float*)d_in[9];
    const float* cq_b1 = (const float*)d_in[10];
    const float* cq_w2 = (const float*)d_in[11];
    const float* cq_b2 = (const float*)d_in[12];
    const float* cq_w3 = (const float*)d_in[13];
    const float* cq_b3 = (const float*)d_in[14];
    float* out = (float*)d_out;

    // ---- workspace: only fuzzy <-> g2 share a region; weights never aliased ----
    const size_t PERSIST = 2097152 + 1048576 + 1048576 + 262144 + 262144 + 1048576;
    const size_t H1SZ = (size_t)65536 * 1024 * 2;   // 134 MB (h1, pass-2: g1)
    const size_t FUZZSZ = (size_t)65536 * 512 * 2;  // 67 MB (fuzzy, pass-2: g2)
    auto need = [&](int p) -> size_t {
        size_t fz = FUZZSZ > (size_t)p * 2097152 ? FUZZSZ : (size_t)p * 2097152;
        return PERSIST + H1SZ + fz + (size_t)p * (1048576 + 1048576 + 131072);
    };
    int p2r = 16;
    while (need(p2r) > ws_size && p2r > 2) p2r >>= 1;

    char* ws = (char*)d_ws;
    size_t off = 0;
    auto take = [&](size_t bytes) { char* p = ws + off; off += bytes; return p; };
    unsigned short* data_bf = (unsigned short*)take(2097152);
    unsigned short* w1t     = (unsigned short*)take(1048576);
    unsigned short* w2t     = (unsigned short*)take(1048576);
    float*          fslog   = (float*)take(262144);
    float*          fire    = (float*)take(262144);
    float*          mix     = (float*)take(1048576);
    unsigned short* h1      = (unsigned short*)take(H1SZ);
    size_t fzsz = FUZZSZ > (size_t)p2r * 2097152 ? FUZZSZ : (size_t)p2r * 2097152;
    unsigned short* fuzzy   = (unsigned short*)take(fzsz);          // pass-2: g2
    unsigned short* cW1t    = (unsigned short*)take((size_t)p2r * 1048576);
    unsigned short* cW2t    = (unsigned short*)take((size_t)p2r * 1048576);
    unsigned short* cW3t    = (unsigned short*)take((size_t)p2r * 131072);
    unsigned short* g1 = h1;
    unsigned short* g2 = fuzzy;

    // ---- prologue ----
    transpose_kernel<<<dim3(16, 32, 1), 256, 0, stream>>>(fs_w1, w1t, 512, 1024, 1024);
    transpose_kernel<<<dim3(32, 16, 1), 256, 0, stream>>>(fs_w2, w2t, 1024, 512, 512);
    hipMemsetAsync(fslog, 0, 262144, stream);
    hipMemsetAsync(mix, 0, 1048576, stream);

    // ---- pass 1: fuzzy(+data cvt) -> GEMM1 -> GEMM2(+fused w3 GEMV) -> fire ----
    // h1 is tile-major: written cT=1 by G1, read aT=1 by G2.
    fuzzy_kernel<<<32768, 256, 0, stream>>>(data, proto, var, fuzzy, data_bf);
    gemm256_kernel<0, true><<<256 * 4, 512, 0, stream>>>(
        fuzzy, w1t, fs_b1, h1, nullptr, nullptr, 256, 4, 512, 0, 0, 0, 0, 0, 1);
    gemm256_kernel<1, true><<<256 * 2, 512, 0, stream>>>(
        h1, w2t, fs_b2, nullptr, fs_w3, fslog, 256, 2, 1024, 0, 0, 0, 0, 1, 0);
    fire_kernel<<<8, 256, 0, stream>>>(fslog, fire);

    // ---- pass 2: consequent chain (g1, g2 tile-major; logits+mixture fused via atomics) ----
    for (int ch = 0; ch < 32 / p2r; ++ch) {
        const int r0 = ch * p2r;
        transpose_kernel<<<dim3(16, 32, p2r), 256, 0, stream>>>(
            cq_w1 + (long)r0 * 512 * 1024, cW1t, 512, 1024, 1024);
        transpose_kernel<<<dim3(32, 16, p2r), 256, 0, stream>>>(
            cq_w2 + (long)r0 * 1024 * 512, cW2t, 1024, 512, 512);
        transpose_kernel<<<dim3(16, 4, p2r), 256, 0, stream>>>(
            cq_w3 + (long)r0 * 512 * 100, cW3t, 512, 100, 128);
        gemm256_kernel<0, true><<<8 * 4 * p2r, 512, 0, stream>>>(
            data_bf, cW1t, cq_b1 + (long)r0 * 1024, g1, nullptr, nullptr,
            8, 4, 512, 0, (long)1024 * 512, (long)2048 * 1024, 1024, 0, 1);
        gemm256_kernel<0, true><<<8 * 2 * p2r, 512, 0, stream>>>(
            g1, cW2t, cq_b2 + (long)r0 * 512, g2, nullptr, nullptr,
            8, 2, 1024, (long)2048 * 1024, (long)512 * 1024, (long)2048 * 512, 512, 1, 1);
        gemm_kernel<3, false><<<16 * 1 * p2r, 256, 0, stream>>>(
            g2, cW3t, cq_b3 + (long)r0 * 100, nullptr,
            16, 1, 512, (long)2048 * 512, (long)128 * 512, 0, 100, 100,
            fire, mix, r0, 1);
    }
    softmax_out_kernel<<<2048, 128, 0, stream>>>(mix, out);
}

// Round 15
// 513.120 us; speedup vs baseline: 1.0193x; 1.0193x over previous
//
#include <hip/hip_runtime.h>

// ---------- types ----------
typedef __attribute__((ext_vector_type(8))) short short8;
typedef __attribute__((ext_vector_type(4))) float f32x4;

__device__ __forceinline__ unsigned short f2bf(float f) {
    union { float f; unsigned u; } v; v.f = f;
    unsigned r = v.u + 0x7FFFu + ((v.u >> 16) & 1u);   // RNE
    return (unsigned short)(r >> 16);
}

// ---------- K1: tiled transpose fp32 [G][K][N] -> bf16 [G][Np][K] ----------
__global__ __launch_bounds__(256)
void transpose_kernel(const float* __restrict__ X, unsigned short* __restrict__ Y,
                      int K, int N, int Np) {
    __shared__ float tile[32][33];
    int g = blockIdx.z;
    const float* Xg = X + (long)g * K * N;
    unsigned short* Yg = Y + (long)g * Np * K;
    int k0 = blockIdx.x * 32, n0 = blockIdx.y * 32;
    int tx = threadIdx.x & 31, ty = threadIdx.x >> 5;
#pragma unroll
    for (int i = 0; i < 4; ++i) {
        int kk = ty + i * 8;
        int n = n0 + tx;
        tile[kk][tx] = (n < N) ? Xg[(long)(k0 + kk) * N + n] : 0.0f;
    }
    __syncthreads();
#pragma unroll
    for (int i = 0; i < 4; ++i) {
        int nn = ty + i * 8;
        Yg[(long)(n0 + nn) * K + k0 + tx] = f2bf(tile[tx][nn]);
    }
}

// ---------- K2: fuzzy membership -> bf16 [R*B, F]; r==0 slice also emits data_bf ----------
__global__ __launch_bounds__(256)
void fuzzy_kernel(const float* __restrict__ data, const float* __restrict__ proto,
                  const float* __restrict__ var, unsigned short* __restrict__ fuzzy,
                  unsigned short* __restrict__ data_bf) {
    int t = threadIdx.x;
    int rb = blockIdx.x * 2 + (t >> 7);          // 32768 blocks x 2 rows
    int r = rb >> 11, b = rb & 2047;
    int f = (t & 127) * 4;
    float4 d = *(const float4*)(data + (long)b * 512 + f);
    float4 p = *(const float4*)(proto + (long)r * 512 + f);
    float4 w = *(const float4*)(var + (long)r * 512 + f);
    ushort4 o;
    float x;
    x = d.x - p.x; o.x = f2bf(__expf(-(x * x) / (2.f * w.x * w.x)));
    x = d.y - p.y; o.y = f2bf(__expf(-(x * x) / (2.f * w.y * w.y)));
    x = d.z - p.z; o.z = f2bf(__expf(-(x * x) / (2.f * w.z * w.z)));
    x = d.w - p.w; o.w = f2bf(__expf(-(x * x) / (2.f * w.w * w.w)));
    *(ushort4*)(fuzzy + (long)rb * 512 + f) = o;
    if (r == 0) {   // fold data -> bf16 conversion into the r==0 slice
        ushort4 od;
        od.x = f2bf(d.x); od.y = f2bf(d.y); od.z = f2bf(d.z); od.w = f2bf(d.w);
        *(ushort4*)(data_bf + (long)b * 512 + f) = od;
    }
}

#define RING_WAIT_BARRIER(n)                                        \
    asm volatile("s_waitcnt vmcnt(" #n ")" ::: "memory");           \
    __builtin_amdgcn_sched_barrier(0);                              \
    __builtin_amdgcn_s_barrier();                                   \
    __builtin_amdgcn_sched_barrier(0);

// ---------- K3: 256x256 ring-4 bf16 MFMA GEMM + full-128KB-restage C epilogue ----------
// (exact structure that PASSED in rounds 4, 5, 8, 10, 11)
// EPI: 0 = bf16 C store via full LDS re-stage, 1 = fused dot w3 -> atomicAdd fslog.
template<int EPI, bool RELU>
__global__ __launch_bounds__(512, 2)
void gemm256_kernel(const unsigned short* __restrict__ A,
                    const unsigned short* __restrict__ Bt,
                    const float* __restrict__ bias,
                    void* __restrict__ Cptr,
                    const float* __restrict__ w3,
                    float* __restrict__ fslog,
                    int nM, int nN, int K,
                    long sAg, long sBg, long sCg, int sBiasG) {
    unsigned tot = gridDim.x, bid = blockIdx.x;
    unsigned sw = (bid & 7u) * (tot >> 3) + (bid >> 3);
    unsigned pg = (unsigned)(nM * nN);
    unsigned g = sw / pg;
    unsigned rem = sw - g * pg;
    const int m0 = (int)(rem / (unsigned)nN) * 256;
    const int n0 = (int)(rem % (unsigned)nN) * 256;
    const int N = nN * 256;
    A += (long)g * sAg; Bt += (long)g * sBg; bias += (long)g * sBiasG;

    __shared__ __align__(16) unsigned short lds[8][8192];   // [0..3]=A ring, [4..7]=B ring

    const int tid = threadIdx.x;
    const int lane = tid & 63;
    const int w = tid >> 6;
    const int wm = w >> 2, wn = w & 3;
    const int r16 = lane & 15, kg = lane >> 4;

    f32x4 acc[8][4];
#pragma unroll
    for (int i = 0; i < 8; ++i)
#pragma unroll
        for (int j = 0; j < 4; ++j) {
            f32x4 z = {0.f, 0.f, 0.f, 0.f};
            acc[i][j] = z;
        }

    const int nsteps = K >> 5;

    auto STAGE = [&](int slot, int kt) {
        const int k0 = kt << 5;
#pragma unroll
        for (int j = 0; j < 2; ++j) {
            int f = j * 512 + tid;
            int row = f >> 2, sl = f & 3;
            int kk = (sl ^ ((row >> 1) & 3)) << 3;     // T2 inverse swizzle on source
            const unsigned short* ga = A + (long)(m0 + row) * K + k0 + kk;
            __builtin_amdgcn_global_load_lds(
                (const __attribute__((address_space(1))) void*)ga,
                (__attribute__((address_space(3))) void*)(&lds[slot][0] + (j * 512 + w * 64) * 8),
                16, 0, 0);
            const unsigned short* gb = Bt + (long)(n0 + row) * K + k0 + kk;
            __builtin_amdgcn_global_load_lds(
                (const __attribute__((address_space(1))) void*)gb,
                (__attribute__((address_space(3))) void*)(&lds[4 + slot][0] + (j * 512 + w * 64) * 8),
                16, 0, 0);
        }
    };

    auto COMPUTE = [&](int slot) {
        short8 aF[8], bF[4];
#pragma unroll
        for (int mt = 0; mt < 8; ++mt) {
            int R = wm * 128 + mt * 16 + r16;
            aF[mt] = *(const short8*)(&lds[slot][0] + R * 32 + ((kg ^ ((R >> 1) & 3)) << 3));
        }
#pragma unroll
        for (int nt = 0; nt < 4; ++nt) {
            int R = wn * 64 + nt * 16 + r16;
            bF[nt] = *(const short8*)(&lds[4 + slot][0] + R * 32 + ((kg ^ ((R >> 1) & 3)) << 3));
        }
        __builtin_amdgcn_s_setprio(1);
#pragma unroll
        for (int mt = 0; mt < 8; ++mt)
#pragma unroll
            for (int nt = 0; nt < 4; ++nt)
                acc[mt][nt] = __builtin_amdgcn_mfma_f32_16x16x32_bf16(
                    aF[mt], bF[nt], acc[mt][nt], 0, 0, 0);
        __builtin_amdgcn_s_setprio(0);
        asm volatile("" ::: "memory");
        __builtin_amdgcn_s_barrier();          // all waves' ds_reads of this slot done
        __builtin_amdgcn_sched_barrier(0);
    };

    STAGE(0, 0); STAGE(1, 1); STAGE(2, 2);
    for (int t = 0; t <= nsteps - 3; ++t) {
        if (t + 3 < nsteps) STAGE((t + 3) & 3, t + 3);
        RING_WAIT_BARRIER(8);
        COMPUTE(t & 3);
    }
    { RING_WAIT_BARRIER(4); COMPUTE((nsteps - 2) & 3); }
    { RING_WAIT_BARRIER(0); COMPUTE((nsteps - 1) & 3); }

    // ---------- epilogue ----------
    if constexpr (EPI == 1) {
        float w3v[4], bv[4];
#pragma unroll
        for (int nt = 0; nt < 4; ++nt) {
            int col = n0 + wn * 64 + nt * 16 + r16;
            w3v[nt] = w3[col];
            bv[nt] = bias[col];
        }
#pragma unroll
        for (int mt = 0; mt < 8; ++mt) {
#pragma unroll
            for (int j = 0; j < 4; ++j) {
                float p = 0.f;
#pragma unroll
                for (int nt = 0; nt < 4; ++nt) {
                    float v = acc[mt][nt][j] + bv[nt];
                    if (RELU) v = fmaxf(v, 0.f);
                    p += v * w3v[nt];
                }
                p += __shfl_xor(p, 1, 64);
                p += __shfl_xor(p, 2, 64);
                p += __shfl_xor(p, 4, 64);
                p += __shfl_xor(p, 8, 64);
                if (r16 == 0) {
                    int row = m0 + wm * 128 + mt * 16 + kg * 4 + j;
                    atomicAdd(&fslog[row], p);
                }
            }
        }
    } else {
        // full 256x256 C tile (bias+relu+bf16) into 128KB LDS, then coalesced stores
        unsigned short* ldsC = &lds[0][0];
        float bv[4];
#pragma unroll
        for (int nt = 0; nt < 4; ++nt) bv[nt] = bias[n0 + wn * 64 + nt * 16 + r16];
#pragma unroll
        for (int mt = 0; mt < 8; ++mt) {
            int rr = wm * 128 + mt * 16 + kg * 4;
#pragma unroll
            for (int nt = 0; nt < 4; ++nt) {
                int cc = wn * 64 + nt * 16 + r16;
#pragma unroll
                for (int j = 0; j < 4; ++j) {
                    float v = acc[mt][nt][j] + bv[nt];
                    if (RELU) v = fmaxf(v, 0.f);
                    ldsC[(rr + j) * 256 + cc] = f2bf(v);
                }
            }
        }
        __syncthreads();
        unsigned short* Cg = (unsigned short*)Cptr + (long)g * sCg;
#pragma unroll
        for (int rnd = 0; rnd < 16; ++rnd) {
            int idx = rnd * 512 + tid;
            int row = idx >> 5;           // 32 8-elem chunks per 256-col row
            int c8 = idx & 31;
            short8 vv = *(const short8*)(ldsC + row * 256 + c8 * 8);
            *(short8*)(Cg + (long)(m0 + row) * N + n0 + c8 * 8) = vv;
        }
    }
}

// ---------- K3b: 128x128 GEMM (m97 structure); EPI 3 = fused fire-weighted atomic mix ----------
template<int EPI, bool RELU>
__global__ __launch_bounds__(256, 2)
void gemm_kernel(const unsigned short* __restrict__ A,
                 const unsigned short* __restrict__ Bt,
                 const float* __restrict__ bias,
                 void* __restrict__ Cptr,
                 int nM, int nN, int K,
                 long sAg, long sBg, long sCg, int sBiasG, int biasN,
                 const float* __restrict__ fire, float* __restrict__ mix, int r0) {
    unsigned tot = gridDim.x;
    unsigned bid = blockIdx.x;
    unsigned sw = (tot & 7u) == 0 ? (bid & 7u) * (tot >> 3) + (bid >> 3) : bid;
    unsigned pg = (unsigned)nM * (unsigned)nN;
    unsigned g = sw / pg;
    unsigned rem = sw - g * pg;
    unsigned mt_ = rem / (unsigned)nN;
    unsigned nt_ = rem - mt_ * (unsigned)nN;
    const int N = nN * 128;
    A += (long)g * sAg;
    Bt += (long)g * sBg;
    bias += (long)g * sBiasG;
    const int m0 = (int)mt_ * 128;
    const int n0 = (int)nt_ * 128;

    __shared__ __align__(16) unsigned short ldsA[128 * 32];
    __shared__ __align__(16) unsigned short ldsB[128 * 32];

    const int tid = threadIdx.x;
    const int lane = tid & 63;
    const int w = tid >> 6;
    const int wm = w >> 1, wn = w & 1;
    const int r16 = lane & 15, kg = lane >> 4;

    f32x4 acc[4][4];
#pragma unroll
    for (int i = 0; i < 4; ++i)
#pragma unroll
        for (int j = 0; j < 4; ++j) {
            f32x4 z = {0.f, 0.f, 0.f, 0.f};
            acc[i][j] = z;
        }

    for (int k0 = 0; k0 < K; k0 += 32) {
#pragma unroll
        for (int j = 0; j < 2; ++j) {
            int t = j * 256 + tid;
            int row = t >> 2, kc = (t & 3) * 8;
            const unsigned short* ga = A + (long)(m0 + row) * K + k0 + kc;
            __builtin_amdgcn_global_load_lds(
                (const __attribute__((address_space(1))) void*)ga,
                (__attribute__((address_space(3))) void*)(ldsA + (j * 256 + w * 64) * 8),
                16, 0, 0);
            const unsigned short* gb = Bt + (long)(n0 + row) * K + k0 + kc;
            __builtin_amdgcn_global_load_lds(
                (const __attribute__((address_space(1))) void*)gb,
                (__attribute__((address_space(3))) void*)(ldsB + (j * 256 + w * 64) * 8),
                16, 0, 0);
        }
        __syncthreads();
        short8 aF[4], bF[4];
#pragma unroll
        for (int mt = 0; mt < 4; ++mt)
            aF[mt] = *(const short8*)(ldsA + (wm * 64 + mt * 16 + r16) * 32 + kg * 8);
#pragma unroll
        for (int nt = 0; nt < 4; ++nt)
            bF[nt] = *(const short8*)(ldsB + (wn * 64 + nt * 16 + r16) * 32 + kg * 8);
#pragma unroll
        for (int mt = 0; mt < 4; ++mt)
#pragma unroll
            for (int nt = 0; nt < 4; ++nt)
                acc[mt][nt] = __builtin_amdgcn_mfma_f32_16x16x32_bf16(
                    aF[mt], bF[nt], acc[mt][nt], 0, 0, 0);
        __syncthreads();
    }

    if constexpr (EPI == 3) {
        float bv[4];
#pragma unroll
        for (int nt = 0; nt < 4; ++nt) {
            int col = n0 + wn * 64 + nt * 16 + r16;
            bv[nt] = (col < biasN) ? bias[col] : 0.f;
        }
#pragma unroll
        for (int mt = 0; mt < 4; ++mt) {
#pragma unroll
            for (int j = 0; j < 4; ++j) {
                int row = m0 + wm * 64 + mt * 16 + kg * 4 + j;   // batch index b
                float f = fire[row * 32 + r0 + (int)g];
#pragma unroll
                for (int nt = 0; nt < 4; ++nt) {
                    int col = n0 + wn * 64 + nt * 16 + r16;
                    float v = acc[mt][nt][j] + bv[nt];
                    atomicAdd(&mix[row * 128 + col], f * v);
                }
            }
        }
    } else {
#pragma unroll
        for (int nt = 0; nt < 4; ++nt) {
            int col = n0 + wn * 64 + nt * 16 + r16;
            float bv = (col < biasN) ? bias[col] : 0.f;
#pragma unroll
            for (int mt = 0; mt < 4; ++mt) {
#pragma unroll
                for (int j = 0; j < 4; ++j) {
                    int row = m0 + wm * 64 + mt * 16 + kg * 4 + j;
                    float v = acc[mt][nt][j] + bv;
                    if (RELU) v = fmaxf(v, 0.f);
                    ((float*)Cptr)[(long)g * sCg + (long)row * N + col] = v;
                }
            }
        }
    }
}

// ---------- K5: fire = softmax over rules ----------
__global__ __launch_bounds__(256)
void fire_kernel(const float* __restrict__ fslog, float* __restrict__ fire) {
    int b = blockIdx.x * 256 + threadIdx.x;
    float v[32];
    float mx = -1e30f;
#pragma unroll
    for (int r = 0; r < 32; ++r) { v[r] = fslog[r * 2048 + b]; mx = fmaxf(mx, v[r]); }
    float s = 0.f;
#pragma unroll
    for (int r = 0; r < 32; ++r) { v[r] = __expf(v[r] - mx); s += v[r]; }
    float inv = 1.f / s;
#pragma unroll
    for (int r = 0; r < 32; ++r) fire[b * 32 + r] = v[r] * inv;
}

// ---------- K7: class softmax ----------
__global__ __launch_bounds__(128)
void softmax_out_kernel(const float* __restrict__ mix, float* __restrict__ out) {
    int b = blockIdx.x, c = threadIdx.x;
    __shared__ float redm[2], reds[2];
    float val = (c < 100) ? mix[b * 128 + c] : -1e30f;
    float m = val;
#pragma unroll
    for (int off = 32; off; off >>= 1) m = fmaxf(m, __shfl_xor(m, off, 64));
    int lane = c & 63, wv = c >> 6;
    if (lane == 0) redm[wv] = m;
    __syncthreads();
    m = fmaxf(redm[0], redm[1]);
    float e = (c < 100) ? __expf(val - m) : 0.f;
    float s = e;
#pragma unroll
    for (int off = 32; off; off >>= 1) s += __shfl_xor(s, off, 64);
    if (lane == 0) reds[wv] = s;
    __syncthreads();
    s = reds[0] + reds[1];
    if (c < 100) out[b * 100 + c] = e / s;
}

// ---------- launch ----------
extern "C" void kernel_launch(void* const* d_in, const int* in_sizes, int n_in,
                              void* d_out, int out_size, void* d_ws, size_t ws_size,
                              hipStream_t stream) {
    const float* data  = (const float*)d_in[0];
    const float* proto = (const float*)d_in[1];
    const float* var   = (const float*)d_in[2];
    const float* fs_w1 = (const float*)d_in[3];
    const float* fs_b1 = (const float*)d_in[4];
    const float* fs_w2 = (const float*)d_in[5];
    const float* fs_b2 = (const float*)d_in[6];
    const float* fs_w3 = (const float*)d_in[7];
    const float* cq_w1 = (const float*)d_in[9];
    const float* cq_b1 = (const float*)d_in[10];
    const float* cq_w2 = (const float*)d_in[11];
    const float* cq_b2 = (const float*)d_in[12];
    const float* cq_w3 = (const float*)d_in[13];
    const float* cq_b3 = (const float*)d_in[14];
    float* out = (float*)d_out;

    // ---- workspace (207 MB total), dataflow-ordered buffer reuse:
    //   h1 lower 67MB : pass-1 h1 rows / pass-2 g1 (16-rule chunk)
    //   h1 upper 67MB : pass-1 h1 rows / after fs-G2 -> cW1t (33.5MB) + cW2t (33.5MB)
    //   fuzzy 67MB    : pass-1 fuzzy / after fs-G1 -> g2 chunk (33.5MB) + cW3t (4.2MB)
    const size_t H1SZ   = (size_t)65536 * 1024 * 2;   // 134,217,728
    const size_t FUZZSZ = (size_t)65536 * 512 * 2;    //  67,108,864
    char* ws = (char*)d_ws;
    size_t off = 0;
    auto take = [&](size_t bytes) { char* p = ws + off; off += bytes; return p; };
    unsigned short* data_bf = (unsigned short*)take(2097152);
    unsigned short* w1t     = (unsigned short*)take(1048576);
    unsigned short* w2t     = (unsigned short*)take(1048576);
    float*          fslog   = (float*)take(262144);
    float*          fire    = (float*)take(262144);
    float*          mix     = (float*)take(1048576);
    unsigned short* h1      = (unsigned short*)take(H1SZ);
    unsigned short* fuzzy   = (unsigned short*)take(FUZZSZ);
    // aliases (element offsets)
    unsigned short* g1   = h1;                                   // 16-rule g1 chunk (67MB)
    unsigned short* cW1t = h1 + (size_t)33554432;                // h1 upper half start
    unsigned short* cW2t = h1 + (size_t)50331648;                // +33.5MB
    unsigned short* g2   = fuzzy;                                // 16-rule g2 chunk (33.5MB)
    unsigned short* cW3t = fuzzy + (size_t)16777216;             // fuzzy+33.5MB
    const int p2r = 16;

    // ---- prologue ----
    transpose_kernel<<<dim3(16, 32, 1), 256, 0, stream>>>(fs_w1, w1t, 512, 1024, 1024);
    transpose_kernel<<<dim3(32, 16, 1), 256, 0, stream>>>(fs_w2, w2t, 1024, 512, 512);
    hipMemsetAsync(fslog, 0, 262144, stream);
    hipMemsetAsync(mix, 0, 1048576, stream);

    // ---- pass 1: fuzzy(+data cvt) -> GEMM1 -> GEMM2(+fused w3 GEMV) -> fire ----
    fuzzy_kernel<<<32768, 256, 0, stream>>>(data, proto, var, fuzzy, data_bf);
    gemm256_kernel<0, true><<<256 * 4, 512, 0, stream>>>(
        fuzzy, w1t, fs_b1, h1, nullptr, nullptr, 256, 4, 512, 0, 0, 0, 0);
    gemm256_kernel<1, true><<<256 * 2, 512, 0, stream>>>(
        h1, w2t, fs_b2, nullptr, fs_w3, fslog, 256, 2, 1024, 0, 0, 0, 0);
    fire_kernel<<<8, 256, 0, stream>>>(fslog, fire);

    // ---- single-shot weight transposes (after h1/fuzzy are dead as pass-1 data) ----
    transpose_kernel<<<dim3(16, 32, 32), 256, 0, stream>>>(cq_w1, cW1t, 512, 1024, 1024);
    transpose_kernel<<<dim3(32, 16, 32), 256, 0, stream>>>(cq_w2, cW2t, 1024, 512, 512);
    transpose_kernel<<<dim3(16, 4, 32), 256, 0, stream>>>(cq_w3, cW3t, 512, 100, 128);

    // ---- pass 2: consequent chain, 2 chunks of 16 rules (logits+mixture fused via atomics) ----
    for (int ch = 0; ch < 32 / p2r; ++ch) {
        const int r0 = ch * p2r;
        gemm256_kernel<0, true><<<8 * 4 * p2r, 512, 0, stream>>>(
            data_bf, cW1t + (long)r0 * 1024 * 512, cq_b1 + (long)r0 * 1024, g1,
            nullptr, nullptr,
            8, 4, 512, 0, (long)1024 * 512, (long)2048 * 1024, 1024);
        gemm256_kernel<0, true><<<8 * 2 * p2r, 512, 0, stream>>>(
            g1, cW2t + (long)r0 * 512 * 1024, cq_b2 + (long)r0 * 512, g2,
            nullptr, nullptr,
            8, 2, 1024, (long)2048 * 1024, (long)512 * 1024, (long)2048 * 512, 512);
        gemm_kernel<3, false><<<16 * 1 * p2r, 256, 0, stream>>>(
            g2, cW3t + (long)r0 * 128 * 512, cq_b3 + (long)r0 * 100, nullptr,
            16, 1, 512, (long)2048 * 512, (long)128 * 512, 0, 100, 100,
            fire, mix, r0);
    }
    softmax_out_kernel<<<2048, 128, 0, stream>>>(mix, out);
}